// Round 4
// baseline (803.905 us; speedup 1.0000x reference)
//
#include <hip/hip_runtime.h>
#include <math.h>

#define NNODES 50000
#define NEDGES 1600000

__device__ __forceinline__ float lrelu(float v) { return v > 0.f ? v : 0.2f * v; }

__device__ __forceinline__ unsigned short f2bf(float f) {  // RNE f32->bf16
    unsigned u = __float_as_uint(f);
    u += 0x7FFFu + ((u >> 16) & 1u);
    return (unsigned short)(u >> 16);
}

// ---- pad x (N x 11) -> xp (N x 12, last col 0) ----
__global__ void padx_kernel(const float* __restrict__ x, float* __restrict__ xp, int N) {
    int t = blockIdx.x * blockDim.x + threadIdx.x;
    if (t >= N * 12) return;
    int n = t / 12, k = t - n * 12;
    xp[t] = (k < 11) ? x[n * 11 + k] : 0.f;
}

// ---- va[k][h] = sum_f W[k][h*F+f] * a[h][f], padded to 8 heads (0 beyond H) ----
template<int DIN, int H, int F>
__global__ void va_kernel(const float* __restrict__ W, const float* __restrict__ a_s,
                          const float* __restrict__ a_d, float* __restrict__ va_s,
                          float* __restrict__ va_d, int DINEFF) {
    int t = threadIdx.x;  // DIN*8 threads, 1 block
    if (t >= DIN * 8) return;
    int k = t / 8, h = t - k * 8;
    float s = 0.f, d = 0.f;
    if (h < H && k < DINEFF) {
        for (int f = 0; f < F; ++f) {
            float w = W[k * (H * F) + h * F + f];
            s = fmaf(w, a_s[h * F + f], s);
            d = fmaf(w, a_d[h * F + f], d);
        }
    }
    va_s[t] = s;
    va_d[t] = d;
}

// ---- asp[n*8+h] = sum_k X[n][k]*va_s[k][h]; adp likewise ----
template<int DIN>
__global__ void alphap_kernel(const float* __restrict__ X, const float* __restrict__ va_s,
                              const float* __restrict__ va_d, float* __restrict__ asp,
                              float* __restrict__ adp, int N) {
    __shared__ float vs[DIN * 8], vd[DIN * 8];
    for (int i = threadIdx.x; i < DIN * 8; i += blockDim.x) { vs[i] = va_s[i]; vd[i] = va_d[i]; }
    __syncthreads();
    int t = blockIdx.x * blockDim.x + threadIdx.x;
    if (t >= N * 8) return;
    int n = t / 8, h = t - n * 8;
    const float* xr = X + (size_t)n * DIN;
    float s = 0.f, d = 0.f;
    for (int k = 0; k < DIN; ++k) {
        float xv = xr[k];
        s = fmaf(xv, vs[k * 8 + h], s);
        d = fmaf(xv, vd[k * 8 + h], d);
    }
    asp[t] = s;
    adp[t] = d;
}

// ---- CSR build ----
__global__ void hist_kernel(const int* __restrict__ dst, int* __restrict__ cnt, int E) {
    int t = blockIdx.x * blockDim.x + threadIdx.x;
    if (t < E) atomicAdd(&cnt[dst[t]], 1);
}

__global__ void scan_kernel(int* __restrict__ cnt, int* __restrict__ off, int N) {
    __shared__ int ls[1024];
    int t = threadIdx.x;
    const int CH = (N + 1023) / 1024;
    int base = t * CH, lim = min(base + CH, N);
    int s = 0;
    for (int i = base; i < lim; ++i) s += cnt[i];
    ls[t] = s;
    __syncthreads();
    for (int o = 1; o < 1024; o <<= 1) {
        int u = (t >= o) ? ls[t - o] : 0;
        __syncthreads();
        ls[t] += u;
        __syncthreads();
    }
    int run = ls[t] - s;
    for (int i = base; i < lim; ++i) { int c = cnt[i]; off[i] = run; run += c; }
    if (t == 1023) off[N] = ls[1023];
    __syncthreads();
    for (int i = base; i < lim; ++i) cnt[i] = off[i];
}

__global__ void scatter_kernel(const int* __restrict__ src, const int* __restrict__ dst,
                               int* __restrict__ cur, int* __restrict__ esrc, int E) {
    int t = blockIdx.x * blockDim.x + threadIdx.x;
    if (t >= E) return;
    int pos = atomicAdd(&cur[dst[t]], 1);
    esrc[pos] = src[t];
}

// ---- layer-1 gather on raw x rows: aggX[n][h][12] = (sum_e att_h * xp[s]) / den_h ----
__global__ void gather1_kernel(const int* __restrict__ off, const int* __restrict__ esrc,
                               const float* __restrict__ asp, const float* __restrict__ adp,
                               const float* __restrict__ xp, float* __restrict__ aggX, int N) {
    int t = blockIdx.x * blockDim.x + threadIdx.x;
    if (t >= N * 3) return;
    int n = t / 3, j = t - n * 3;
    const float4 advA = *(const float4*)(adp + (size_t)n * 8);
    const float4 advB = *(const float4*)(adp + (size_t)n * 8 + 4);
    const float4* xp4 = (const float4*)xp;
    int p0 = off[n], p1 = off[n + 1];
    float4 ac0 = {0,0,0,0}, ac1 = {0,0,0,0}, ac2 = {0,0,0,0}, ac3 = {0,0,0,0}, ac4 = {0,0,0,0}, ac5 = {0,0,0,0};
    float d0 = 0, d1 = 0, d2 = 0, d3 = 0, d4 = 0, d5 = 0;
    for (int p = p0; p < p1; ++p) {
        int s = esrc[p];
        const float4 asA = *(const float4*)(asp + (size_t)s * 8);
        const float4 asB = *(const float4*)(asp + (size_t)s * 8 + 4);
        float4 xv = xp4[(size_t)s * 3 + j];
        float a0 = __expf(lrelu(asA.x + advA.x));
        float a1 = __expf(lrelu(asA.y + advA.y));
        float a2 = __expf(lrelu(asA.z + advA.z));
        float a3 = __expf(lrelu(asA.w + advA.w));
        float a4 = __expf(lrelu(asB.x + advB.x));
        float a5 = __expf(lrelu(asB.y + advB.y));
        d0 += a0; d1 += a1; d2 += a2; d3 += a3; d4 += a4; d5 += a5;
        ac0.x = fmaf(a0, xv.x, ac0.x); ac0.y = fmaf(a0, xv.y, ac0.y); ac0.z = fmaf(a0, xv.z, ac0.z); ac0.w = fmaf(a0, xv.w, ac0.w);
        ac1.x = fmaf(a1, xv.x, ac1.x); ac1.y = fmaf(a1, xv.y, ac1.y); ac1.z = fmaf(a1, xv.z, ac1.z); ac1.w = fmaf(a1, xv.w, ac1.w);
        ac2.x = fmaf(a2, xv.x, ac2.x); ac2.y = fmaf(a2, xv.y, ac2.y); ac2.z = fmaf(a2, xv.z, ac2.z); ac2.w = fmaf(a2, xv.w, ac2.w);
        ac3.x = fmaf(a3, xv.x, ac3.x); ac3.y = fmaf(a3, xv.y, ac3.y); ac3.z = fmaf(a3, xv.z, ac3.z); ac3.w = fmaf(a3, xv.w, ac3.w);
        ac4.x = fmaf(a4, xv.x, ac4.x); ac4.y = fmaf(a4, xv.y, ac4.y); ac4.z = fmaf(a4, xv.z, ac4.z); ac4.w = fmaf(a4, xv.w, ac4.w);
        ac5.x = fmaf(a5, xv.x, ac5.x); ac5.y = fmaf(a5, xv.y, ac5.y); ac5.z = fmaf(a5, xv.z, ac5.z); ac5.w = fmaf(a5, xv.w, ac5.w);
    }
    float4* o4 = (float4*)aggX;
    float r;
    r = 1.f / (d0 + 1e-12f); ac0.x *= r; ac0.y *= r; ac0.z *= r; ac0.w *= r; o4[((size_t)n * 6 + 0) * 3 + j] = ac0;
    r = 1.f / (d1 + 1e-12f); ac1.x *= r; ac1.y *= r; ac1.z *= r; ac1.w *= r; o4[((size_t)n * 6 + 1) * 3 + j] = ac1;
    r = 1.f / (d2 + 1e-12f); ac2.x *= r; ac2.y *= r; ac2.z *= r; ac2.w *= r; o4[((size_t)n * 6 + 2) * 3 + j] = ac2;
    r = 1.f / (d3 + 1e-12f); ac3.x *= r; ac3.y *= r; ac3.z *= r; ac3.w *= r; o4[((size_t)n * 6 + 3) * 3 + j] = ac3;
    r = 1.f / (d4 + 1e-12f); ac4.x *= r; ac4.y *= r; ac4.z *= r; ac4.w *= r; o4[((size_t)n * 6 + 4) * 3 + j] = ac4;
    r = 1.f / (d5 + 1e-12f); ac5.x *= r; ac5.y *= r; ac5.z *= r; ac5.w *= r; o4[((size_t)n * 6 + 5) * 3 + j] = ac5;
}

// ---- out1[n][96] = elu( aggX[n][h] @ W1[:, head block] ) ----
__global__ void gemmL1_kernel(const float* __restrict__ aggX, const float* __restrict__ W1,
                              float* __restrict__ out1, int N) {
    __shared__ float Wl[12 * 96];
    for (int i = threadIdx.x; i < 12 * 96; i += blockDim.x) Wl[i] = (i < 11 * 96) ? W1[i] : 0.f;
    __syncthreads();
    int t = blockIdx.x * blockDim.x + threadIdx.x;
    if (t >= N * 24) return;
    int n = t / 24, q = t - n * 24;
    int h = q / 4, c = q * 4;
    const float* ag = aggX + ((size_t)n * 6 + h) * 12;
    float4 acc = {0, 0, 0, 0};
#pragma unroll
    for (int k = 0; k < 12; ++k) {
        float xv = ag[k];
        acc.x = fmaf(xv, Wl[k * 96 + c + 0], acc.x);
        acc.y = fmaf(xv, Wl[k * 96 + c + 1], acc.y);
        acc.z = fmaf(xv, Wl[k * 96 + c + 2], acc.z);
        acc.w = fmaf(xv, Wl[k * 96 + c + 3], acc.w);
    }
    acc.x = acc.x > 0.f ? acc.x : expm1f(acc.x);
    acc.y = acc.y > 0.f ? acc.y : expm1f(acc.y);
    acc.z = acc.z > 0.f ? acc.z : expm1f(acc.z);
    acc.w = acc.w > 0.f ? acc.w : expm1f(acc.w);
    ((float4*)out1)[(size_t)n * 24 + q] = acc;
}

// ---- h2 = out1 @ W2, stored bf16 (RNE), thread = (node pair, quad) ----
template<int DIN, int C, int NPT>
__global__ void gemm_bf16_kernel(const float* __restrict__ X, const float* __restrict__ W,
                                 uint2* __restrict__ Out, int N) {
    constexpr int Q = C / 4;
    __shared__ float4 Wl[DIN * Q];
    for (int i = threadIdx.x; i < DIN * Q; i += blockDim.x) Wl[i] = ((const float4*)W)[i];
    __syncthreads();
    int t = blockIdx.x * blockDim.x + threadIdx.x;
    int g = t / Q, q = t - g * Q;
    int n0 = g * NPT;
    if (n0 >= N) return;
    const float* xr = X + (size_t)n0 * DIN;
    float4 acc[NPT];
#pragma unroll
    for (int u = 0; u < NPT; ++u) acc[u] = make_float4(0.f, 0.f, 0.f, 0.f);
#pragma unroll 4
    for (int k = 0; k < DIN; ++k) {
        float4 w = Wl[k * Q + q];
#pragma unroll
        for (int u = 0; u < NPT; ++u) {
            float xv = xr[(size_t)u * DIN + k];
            acc[u].x = fmaf(xv, w.x, acc[u].x);
            acc[u].y = fmaf(xv, w.y, acc[u].y);
            acc[u].z = fmaf(xv, w.z, acc[u].z);
            acc[u].w = fmaf(xv, w.w, acc[u].w);
        }
    }
#pragma unroll
    for (int u = 0; u < NPT; ++u) {
        uint2 pk;
        pk.x = (unsigned)f2bf(acc[u].x) | ((unsigned)f2bf(acc[u].y) << 16);
        pk.y = (unsigned)f2bf(acc[u].z) | ((unsigned)f2bf(acc[u].w) << 16);
        Out[(size_t)(n0 + u) * Q + q] = pk;
    }
}

// ---- layer-2 gather on bf16 h2 table, XCD-pinned channel groups, fused elu+pool ----
// groups: g<4 -> quads [5g,5g+5), 5 thr/node, 51 nodes/block; g>=4 -> quads [20+4(g-4),+4), 4 thr/node, 64 nodes/block
__global__ void gather2_kernel(const int* __restrict__ off, const int* __restrict__ esrc,
                               const float* __restrict__ asp, const float* __restrict__ adp,
                               const uint2* __restrict__ h2t, float* __restrict__ pooled, int N) {
    __shared__ float sp[20];
    if (threadIdx.x < 20) sp[threadIdx.x] = 0.f;
    __syncthreads();
    int g = blockIdx.x & 7;
    int k = blockIdx.x >> 3;
    int qcnt = (g < 4) ? 5 : 4;
    int qbase = (g < 4) ? 5 * g : 20 + 4 * (g - 4);
    int npb = (g < 4) ? 51 : 64;
    int li = threadIdx.x;
    int node = k * npb + li / qcnt;
    int j = li - (li / qcnt) * qcnt;
    if (li < npb * qcnt && node < N) {
        int quad = qbase + j;
        int h = quad / 6;
        float adv = adp[(size_t)node * 8 + h];
        int p0 = off[node], p1 = off[node + 1];
        float4 acc = {0, 0, 0, 0};
        float den = 0.f;
        for (int p = p0; p < p1; ++p) {
            int s = esrc[p];
            float att = __expf(lrelu(asp[(size_t)s * 8 + h] + adv));
            den += att;
            uint2 hv = h2t[(size_t)s * 36 + quad];
            float c0 = __uint_as_float(hv.x << 16);
            float c1 = __uint_as_float(hv.x & 0xFFFF0000u);
            float c2 = __uint_as_float(hv.y << 16);
            float c3 = __uint_as_float(hv.y & 0xFFFF0000u);
            acc.x = fmaf(att, c0, acc.x);
            acc.y = fmaf(att, c1, acc.y);
            acc.z = fmaf(att, c2, acc.z);
            acc.w = fmaf(att, c3, acc.w);
        }
        float r = 1.f / (den + 1e-12f);
        acc.x *= r; acc.y *= r; acc.z *= r; acc.w *= r;
        acc.x = acc.x > 0.f ? acc.x : expm1f(acc.x);
        acc.y = acc.y > 0.f ? acc.y : expm1f(acc.y);
        acc.z = acc.z > 0.f ? acc.z : expm1f(acc.z);
        acc.w = acc.w > 0.f ? acc.w : expm1f(acc.w);
        atomicAdd(&sp[j * 4 + 0], acc.x);
        atomicAdd(&sp[j * 4 + 1], acc.y);
        atomicAdd(&sp[j * 4 + 2], acc.z);
        atomicAdd(&sp[j * 4 + 3], acc.w);
    }
    __syncthreads();
    if (threadIdx.x < qcnt * 4) atomicAdd(&pooled[qbase * 4 + threadIdx.x], sp[threadIdx.x]);
}

// ---- out = dot(pooled, Wd) / max(||pooled||, 1e-12) + bd ----
__global__ void final_kernel(const float* __restrict__ pooled, const float* __restrict__ Wd,
                             const float* __restrict__ bd, float* __restrict__ out) {
    int l = threadIdx.x;
    float ss = 0.f, dot = 0.f;
    for (int c = l; c < 144; c += 64) {
        float p = pooled[c];
        ss = fmaf(p, p, ss);
        dot = fmaf(p, Wd[c], dot);
    }
#pragma unroll
    for (int o = 32; o > 0; o >>= 1) {
        ss += __shfl_down(ss, o);
        dot += __shfl_down(dot, o);
    }
    if (l == 0) out[0] = dot / fmaxf(sqrtf(ss), 1e-12f) + bd[0];
}

extern "C" void kernel_launch(void* const* d_in, const int* in_sizes, int n_in,
                              void* d_out, int out_size, void* d_ws, size_t ws_size,
                              hipStream_t stream) {
    const float* x   = (const float*)d_in[0];
    const int*   src = (const int*)  d_in[1];
    const int*   dst = (const int*)  d_in[2];
    const float* W1  = (const float*)d_in[3];
    const float* a1s = (const float*)d_in[4];
    const float* a1d = (const float*)d_in[5];
    const float* W2  = (const float*)d_in[6];
    const float* a2s = (const float*)d_in[7];
    const float* a2d = (const float*)d_in[8];
    const float* Wd  = (const float*)d_in[9];
    const float* bd  = (const float*)d_in[10];

    const int N = NNODES, E = NEDGES;
    float* ws = (float*)d_ws;
    float* xp    = ws;                         // N*12          = 0.6M
    float* asp1  = xp + (size_t)N * 12;        // N*8           = 0.4M
    float* adp1  = asp1 + (size_t)N * 8;       // N*8
    float* aggX  = adp1 + (size_t)N * 8;       // N*72          = 3.6M
    float* out1  = aggX + (size_t)N * 72;      // N*96          = 4.8M
    uint2* h2t   = (uint2*)(out1 + (size_t)N * 96);   // N*36 uint2 (= N*144 bf16)
    float* asp2  = out1 + (size_t)N * 96 + (size_t)N * 72;  // N*8
    float* adp2  = asp2 + (size_t)N * 8;       // N*8
    float* va1s  = adp2 + (size_t)N * 8;       // 96
    float* va1d  = va1s + 96;                  // 96
    float* va2s  = va1d + 96;                  // 768
    float* va2d  = va2s + 768;                 // 768
    float* pooled = va2d + 768;                // 144
    int*   off   = (int*)(pooled + 144);       // N+1
    int*   cur   = off + (N + 1);              // N
    int*   esrc  = cur + N;                    // E

    const int B = 256;
    auto grid = [](long total, int b) { return (int)((total + b - 1) / b); };

    // ---- CSR build ----
    hipMemsetAsync(cur, 0, (size_t)N * sizeof(int), stream);
    hist_kernel<<<grid(E, B), B, 0, stream>>>(dst, cur, E);
    scan_kernel<<<1, 1024, 0, stream>>>(cur, off, N);
    scatter_kernel<<<grid(E, B), B, 0, stream>>>(src, dst, cur, esrc, E);

    // ---- layer 1 (gather raw x, GEMM after) ----
    padx_kernel<<<grid((long)N * 12, B), B, 0, stream>>>(x, xp, N);
    va_kernel<12, 6, 16><<<1, 96, 0, stream>>>(W1, a1s, a1d, va1s, va1d, 11);
    alphap_kernel<12><<<grid((long)N * 8, B), B, 0, stream>>>(xp, va1s, va1d, asp1, adp1, N);
    gather1_kernel<<<grid((long)N * 3, B), B, 0, stream>>>(off, esrc, asp1, adp1, xp, aggX, N);
    gemmL1_kernel<<<grid((long)N * 24, B), B, 0, stream>>>(aggX, W1, out1, N);

    // ---- layer 2 (bf16 message table, alphas exact from out1) ----
    va_kernel<96, 6, 24><<<1, 768, 0, stream>>>(W2, a2s, a2d, va2s, va2d, 96);
    alphap_kernel<96><<<grid((long)N * 8, B), B, 0, stream>>>(out1, va2s, va2d, asp2, adp2, N);
    gemm_bf16_kernel<96, 144, 2><<<grid((long)(N / 2) * 36, B), B, 0, stream>>>(out1, W2, h2t, N);
    hipMemsetAsync(pooled, 0, 144 * sizeof(float), stream);
    gather2_kernel<<<981 * 8, B, 0, stream>>>(off, esrc, asp2, adp2, h2t, pooled, N);

    // ---- normalize + linear ----
    final_kernel<<<1, 64, 0, stream>>>(pooled, Wd, bd, (float*)d_out);
}

// Round 5
// 630.985 us; speedup vs baseline: 1.2740x; 1.2740x over previous
//
#include <hip/hip_runtime.h>
#include <math.h>

#define NNODES 50000
#define NEDGES 1600000

__device__ __forceinline__ float lrelu(float v) { return v > 0.f ? v : 0.2f * v; }

__device__ __forceinline__ unsigned short f2bf(float f) {  // RNE f32->bf16
    unsigned u = __float_as_uint(f);
    u += 0x7FFFu + ((u >> 16) & 1u);
    return (unsigned short)(u >> 16);
}

// ---- pad x (N x 11) -> xp (N x 12, last col 0) ----
__global__ void padx_kernel(const float* __restrict__ x, float* __restrict__ xp, int N) {
    int t = blockIdx.x * blockDim.x + threadIdx.x;
    if (t >= N * 12) return;
    int n = t / 12, k = t - n * 12;
    xp[t] = (k < 11) ? x[n * 11 + k] : 0.f;
}

// ---- va[k][h] = sum_f W[k][h*F+f] * a[h][f], padded to 8 heads (0 beyond H) ----
template<int DIN, int H, int F>
__global__ void va_kernel(const float* __restrict__ W, const float* __restrict__ a_s,
                          const float* __restrict__ a_d, float* __restrict__ va_s,
                          float* __restrict__ va_d, int DINEFF) {
    int t = threadIdx.x;  // DIN*8 threads, 1 block
    if (t >= DIN * 8) return;
    int k = t / 8, h = t - k * 8;
    float s = 0.f, d = 0.f;
    if (h < H && k < DINEFF) {
        for (int f = 0; f < F; ++f) {
            float w = W[k * (H * F) + h * F + f];
            s = fmaf(w, a_s[h * F + f], s);
            d = fmaf(w, a_d[h * F + f], d);
        }
    }
    va_s[t] = s;
    va_d[t] = d;
}

// ---- asp[n*8+h] = sum_k X[n][k]*va_s[k][h]; adp likewise ----
template<int DIN>
__global__ void alphap_kernel(const float* __restrict__ X, const float* __restrict__ va_s,
                              const float* __restrict__ va_d, float* __restrict__ asp,
                              float* __restrict__ adp, int N) {
    __shared__ float vs[DIN * 8], vd[DIN * 8];
    for (int i = threadIdx.x; i < DIN * 8; i += blockDim.x) { vs[i] = va_s[i]; vd[i] = va_d[i]; }
    __syncthreads();
    int t = blockIdx.x * blockDim.x + threadIdx.x;
    if (t >= N * 8) return;
    int n = t / 8, h = t - n * 8;
    const float* xr = X + (size_t)n * DIN;
    float s = 0.f, d = 0.f;
    for (int k = 0; k < DIN; ++k) {
        float xv = xr[k];
        s = fmaf(xv, vs[k * 8 + h], s);
        d = fmaf(xv, vd[k * 8 + h], d);
    }
    asp[t] = s;
    adp[t] = d;
}

// ---- CSR build ----
__global__ void hist_kernel(const int* __restrict__ dst, int* __restrict__ cnt, int E) {
    int t = blockIdx.x * blockDim.x + threadIdx.x;
    if (t < E) atomicAdd(&cnt[dst[t]], 1);
}

__global__ void scan_kernel(int* __restrict__ cnt, int* __restrict__ off, int N) {
    __shared__ int ls[1024];
    int t = threadIdx.x;
    const int CH = (N + 1023) / 1024;
    int base = t * CH, lim = min(base + CH, N);
    int s = 0;
    for (int i = base; i < lim; ++i) s += cnt[i];
    ls[t] = s;
    __syncthreads();
    for (int o = 1; o < 1024; o <<= 1) {
        int u = (t >= o) ? ls[t - o] : 0;
        __syncthreads();
        ls[t] += u;
        __syncthreads();
    }
    int run = ls[t] - s;
    for (int i = base; i < lim; ++i) { int c = cnt[i]; off[i] = run; run += c; }
    if (t == 1023) off[N] = ls[1023];
    __syncthreads();
    for (int i = base; i < lim; ++i) cnt[i] = off[i];
}

__global__ void scatter_kernel(const int* __restrict__ src, const int* __restrict__ dst,
                               int* __restrict__ cur, int* __restrict__ esrc, int E) {
    int t = blockIdx.x * blockDim.x + threadIdx.x;
    if (t >= E) return;
    int pos = atomicAdd(&cur[dst[t]], 1);
    esrc[pos] = src[t];
}

// ---- layer-1 gather on raw x rows: aggX[n][h][12] = (sum_e att_h * xp[s]) / den_h ----
__global__ void gather1_kernel(const int* __restrict__ off, const int* __restrict__ esrc,
                               const float* __restrict__ asp, const float* __restrict__ adp,
                               const float* __restrict__ xp, float* __restrict__ aggX, int N) {
    int t = blockIdx.x * blockDim.x + threadIdx.x;
    if (t >= N * 3) return;
    int n = t / 3, j = t - n * 3;
    const float4 advA = *(const float4*)(adp + (size_t)n * 8);
    const float4 advB = *(const float4*)(adp + (size_t)n * 8 + 4);
    const float4* xp4 = (const float4*)xp;
    int p0 = off[n], p1 = off[n + 1];
    float4 ac0 = {0,0,0,0}, ac1 = {0,0,0,0}, ac2 = {0,0,0,0}, ac3 = {0,0,0,0}, ac4 = {0,0,0,0}, ac5 = {0,0,0,0};
    float d0 = 0, d1 = 0, d2 = 0, d3 = 0, d4 = 0, d5 = 0;
    for (int p = p0; p < p1; ++p) {
        int s = esrc[p];
        const float4 asA = *(const float4*)(asp + (size_t)s * 8);
        const float4 asB = *(const float4*)(asp + (size_t)s * 8 + 4);
        float4 xv = xp4[(size_t)s * 3 + j];
        float a0 = __expf(lrelu(asA.x + advA.x));
        float a1 = __expf(lrelu(asA.y + advA.y));
        float a2 = __expf(lrelu(asA.z + advA.z));
        float a3 = __expf(lrelu(asA.w + advA.w));
        float a4 = __expf(lrelu(asB.x + advB.x));
        float a5 = __expf(lrelu(asB.y + advB.y));
        d0 += a0; d1 += a1; d2 += a2; d3 += a3; d4 += a4; d5 += a5;
        ac0.x = fmaf(a0, xv.x, ac0.x); ac0.y = fmaf(a0, xv.y, ac0.y); ac0.z = fmaf(a0, xv.z, ac0.z); ac0.w = fmaf(a0, xv.w, ac0.w);
        ac1.x = fmaf(a1, xv.x, ac1.x); ac1.y = fmaf(a1, xv.y, ac1.y); ac1.z = fmaf(a1, xv.z, ac1.z); ac1.w = fmaf(a1, xv.w, ac1.w);
        ac2.x = fmaf(a2, xv.x, ac2.x); ac2.y = fmaf(a2, xv.y, ac2.y); ac2.z = fmaf(a2, xv.z, ac2.z); ac2.w = fmaf(a2, xv.w, ac2.w);
        ac3.x = fmaf(a3, xv.x, ac3.x); ac3.y = fmaf(a3, xv.y, ac3.y); ac3.z = fmaf(a3, xv.z, ac3.z); ac3.w = fmaf(a3, xv.w, ac3.w);
        ac4.x = fmaf(a4, xv.x, ac4.x); ac4.y = fmaf(a4, xv.y, ac4.y); ac4.z = fmaf(a4, xv.z, ac4.z); ac4.w = fmaf(a4, xv.w, ac4.w);
        ac5.x = fmaf(a5, xv.x, ac5.x); ac5.y = fmaf(a5, xv.y, ac5.y); ac5.z = fmaf(a5, xv.z, ac5.z); ac5.w = fmaf(a5, xv.w, ac5.w);
    }
    float4* o4 = (float4*)aggX;
    float r;
    r = 1.f / (d0 + 1e-12f); ac0.x *= r; ac0.y *= r; ac0.z *= r; ac0.w *= r; o4[((size_t)n * 6 + 0) * 3 + j] = ac0;
    r = 1.f / (d1 + 1e-12f); ac1.x *= r; ac1.y *= r; ac1.z *= r; ac1.w *= r; o4[((size_t)n * 6 + 1) * 3 + j] = ac1;
    r = 1.f / (d2 + 1e-12f); ac2.x *= r; ac2.y *= r; ac2.z *= r; ac2.w *= r; o4[((size_t)n * 6 + 2) * 3 + j] = ac2;
    r = 1.f / (d3 + 1e-12f); ac3.x *= r; ac3.y *= r; ac3.z *= r; ac3.w *= r; o4[((size_t)n * 6 + 3) * 3 + j] = ac3;
    r = 1.f / (d4 + 1e-12f); ac4.x *= r; ac4.y *= r; ac4.z *= r; ac4.w *= r; o4[((size_t)n * 6 + 4) * 3 + j] = ac4;
    r = 1.f / (d5 + 1e-12f); ac5.x *= r; ac5.y *= r; ac5.z *= r; ac5.w *= r; o4[((size_t)n * 6 + 5) * 3 + j] = ac5;
}

// ---- out1[n][96] = elu( aggX[n][h] @ W1[:, head block] ) ----
__global__ void gemmL1_kernel(const float* __restrict__ aggX, const float* __restrict__ W1,
                              float* __restrict__ out1, int N) {
    __shared__ float Wl[12 * 96];
    for (int i = threadIdx.x; i < 12 * 96; i += blockDim.x) Wl[i] = (i < 11 * 96) ? W1[i] : 0.f;
    __syncthreads();
    int t = blockIdx.x * blockDim.x + threadIdx.x;
    if (t >= N * 24) return;
    int n = t / 24, q = t - n * 24;
    int h = q / 4, c = q * 4;
    const float* ag = aggX + ((size_t)n * 6 + h) * 12;
    float4 acc = {0, 0, 0, 0};
#pragma unroll
    for (int k = 0; k < 12; ++k) {
        float xv = ag[k];
        acc.x = fmaf(xv, Wl[k * 96 + c + 0], acc.x);
        acc.y = fmaf(xv, Wl[k * 96 + c + 1], acc.y);
        acc.z = fmaf(xv, Wl[k * 96 + c + 2], acc.z);
        acc.w = fmaf(xv, Wl[k * 96 + c + 3], acc.w);
    }
    acc.x = acc.x > 0.f ? acc.x : expm1f(acc.x);
    acc.y = acc.y > 0.f ? acc.y : expm1f(acc.y);
    acc.z = acc.z > 0.f ? acc.z : expm1f(acc.z);
    acc.w = acc.w > 0.f ? acc.w : expm1f(acc.w);
    ((float4*)out1)[(size_t)n * 24 + q] = acc;
}

// ---- h2 = out1 @ W2, stored bf16 (RNE), thread = (node pair, quad) ----
template<int DIN, int C, int NPT>
__global__ void gemm_bf16_kernel(const float* __restrict__ X, const float* __restrict__ W,
                                 uint2* __restrict__ Out, int N) {
    constexpr int Q = C / 4;
    __shared__ float4 Wl[DIN * Q];
    for (int i = threadIdx.x; i < DIN * Q; i += blockDim.x) Wl[i] = ((const float4*)W)[i];
    __syncthreads();
    int t = blockIdx.x * blockDim.x + threadIdx.x;
    int g = t / Q, q = t - g * Q;
    int n0 = g * NPT;
    if (n0 >= N) return;
    const float* xr = X + (size_t)n0 * DIN;
    float4 acc[NPT];
#pragma unroll
    for (int u = 0; u < NPT; ++u) acc[u] = make_float4(0.f, 0.f, 0.f, 0.f);
#pragma unroll 4
    for (int k = 0; k < DIN; ++k) {
        float4 w = Wl[k * Q + q];
#pragma unroll
        for (int u = 0; u < NPT; ++u) {
            float xv = xr[(size_t)u * DIN + k];
            acc[u].x = fmaf(xv, w.x, acc[u].x);
            acc[u].y = fmaf(xv, w.y, acc[u].y);
            acc[u].z = fmaf(xv, w.z, acc[u].z);
            acc[u].w = fmaf(xv, w.w, acc[u].w);
        }
    }
#pragma unroll
    for (int u = 0; u < NPT; ++u) {
        uint2 pk;
        pk.x = (unsigned)f2bf(acc[u].x) | ((unsigned)f2bf(acc[u].y) << 16);
        pk.y = (unsigned)f2bf(acc[u].z) | ((unsigned)f2bf(acc[u].w) << 16);
        Out[(size_t)(n0 + u) * Q + q] = pk;
    }
}

// ---- layer-2 gather: full bf16 row per node (36 quads, adjacent lanes), fused elu+pool ----
// block = 576 threads = 16 nodes x 36 quads (9 full waves)
__global__ void gather2_kernel(const int* __restrict__ off, const int* __restrict__ esrc,
                               const float* __restrict__ asp, const float* __restrict__ adp,
                               const uint2* __restrict__ h2t, float* __restrict__ pooled, int N) {
    __shared__ float sp[144];
    if (threadIdx.x < 144) sp[threadIdx.x] = 0.f;
    __syncthreads();
    int li = threadIdx.x;
    int node = blockIdx.x * 16 + li / 36;
    int q = li % 36;           // channels [4q, 4q+4)
    if (node < N) {
        int h = q / 6;         // head = (4q)/24
        float adv = adp[(size_t)node * 8 + h];
        int p0 = off[node], p1 = off[node + 1];
        float4 acc = {0, 0, 0, 0};
        float den = 0.f;
        for (int p = p0; p < p1; ++p) {
            int s = esrc[p];
            float att = __expf(lrelu(asp[(size_t)s * 8 + h] + adv));
            den += att;
            uint2 hv = h2t[(size_t)s * 36 + q];
            float c0 = __uint_as_float(hv.x << 16);
            float c1 = __uint_as_float(hv.x & 0xFFFF0000u);
            float c2 = __uint_as_float(hv.y << 16);
            float c3 = __uint_as_float(hv.y & 0xFFFF0000u);
            acc.x = fmaf(att, c0, acc.x);
            acc.y = fmaf(att, c1, acc.y);
            acc.z = fmaf(att, c2, acc.z);
            acc.w = fmaf(att, c3, acc.w);
        }
        float r = 1.f / (den + 1e-12f);
        acc.x *= r; acc.y *= r; acc.z *= r; acc.w *= r;
        acc.x = acc.x > 0.f ? acc.x : expm1f(acc.x);
        acc.y = acc.y > 0.f ? acc.y : expm1f(acc.y);
        acc.z = acc.z > 0.f ? acc.z : expm1f(acc.z);
        acc.w = acc.w > 0.f ? acc.w : expm1f(acc.w);
        atomicAdd(&sp[q * 4 + 0], acc.x);
        atomicAdd(&sp[q * 4 + 1], acc.y);
        atomicAdd(&sp[q * 4 + 2], acc.z);
        atomicAdd(&sp[q * 4 + 3], acc.w);
    }
    __syncthreads();
    if (threadIdx.x < 144) atomicAdd(&pooled[threadIdx.x], sp[threadIdx.x]);
}

// ---- out = dot(pooled, Wd) / max(||pooled||, 1e-12) + bd ----
__global__ void final_kernel(const float* __restrict__ pooled, const float* __restrict__ Wd,
                             const float* __restrict__ bd, float* __restrict__ out) {
    int l = threadIdx.x;
    float ss = 0.f, dot = 0.f;
    for (int c = l; c < 144; c += 64) {
        float p = pooled[c];
        ss = fmaf(p, p, ss);
        dot = fmaf(p, Wd[c], dot);
    }
#pragma unroll
    for (int o = 32; o > 0; o >>= 1) {
        ss += __shfl_down(ss, o);
        dot += __shfl_down(dot, o);
    }
    if (l == 0) out[0] = dot / fmaxf(sqrtf(ss), 1e-12f) + bd[0];
}

extern "C" void kernel_launch(void* const* d_in, const int* in_sizes, int n_in,
                              void* d_out, int out_size, void* d_ws, size_t ws_size,
                              hipStream_t stream) {
    const float* x   = (const float*)d_in[0];
    const int*   src = (const int*)  d_in[1];
    const int*   dst = (const int*)  d_in[2];
    const float* W1  = (const float*)d_in[3];
    const float* a1s = (const float*)d_in[4];
    const float* a1d = (const float*)d_in[5];
    const float* W2  = (const float*)d_in[6];
    const float* a2s = (const float*)d_in[7];
    const float* a2d = (const float*)d_in[8];
    const float* Wd  = (const float*)d_in[9];
    const float* bd  = (const float*)d_in[10];

    const int N = NNODES, E = NEDGES;
    float* ws = (float*)d_ws;
    float* xp    = ws;                         // N*12
    float* asp1  = xp + (size_t)N * 12;        // N*8
    float* adp1  = asp1 + (size_t)N * 8;       // N*8
    float* aggX  = adp1 + (size_t)N * 8;       // N*72
    float* out1  = aggX + (size_t)N * 72;      // N*96
    uint2* h2t   = (uint2*)(out1 + (size_t)N * 96);   // N*36 uint2 (= N*144 bf16)
    float* asp2  = out1 + (size_t)N * 96 + (size_t)N * 72;  // N*8
    float* adp2  = asp2 + (size_t)N * 8;       // N*8
    float* va1s  = adp2 + (size_t)N * 8;       // 96
    float* va1d  = va1s + 96;                  // 96
    float* va2s  = va1d + 96;                  // 768
    float* va2d  = va2s + 768;                 // 768
    float* pooled = va2d + 768;                // 144
    int*   off   = (int*)(pooled + 144);       // N+1
    int*   cur   = off + (N + 1);              // N
    int*   esrc  = cur + N;                    // E

    const int B = 256;
    auto grid = [](long total, int b) { return (int)((total + b - 1) / b); };

    // ---- CSR build ----
    hipMemsetAsync(cur, 0, (size_t)N * sizeof(int), stream);
    hist_kernel<<<grid(E, B), B, 0, stream>>>(dst, cur, E);
    scan_kernel<<<1, 1024, 0, stream>>>(cur, off, N);
    scatter_kernel<<<grid(E, B), B, 0, stream>>>(src, dst, cur, esrc, E);

    // ---- layer 1 (gather raw x, GEMM after) ----
    padx_kernel<<<grid((long)N * 12, B), B, 0, stream>>>(x, xp, N);
    va_kernel<12, 6, 16><<<1, 96, 0, stream>>>(W1, a1s, a1d, va1s, va1d, 11);
    alphap_kernel<12><<<grid((long)N * 8, B), B, 0, stream>>>(xp, va1s, va1d, asp1, adp1, N);
    gather1_kernel<<<grid((long)N * 3, B), B, 0, stream>>>(off, esrc, asp1, adp1, xp, aggX, N);
    gemmL1_kernel<<<grid((long)N * 24, B), B, 0, stream>>>(aggX, W1, out1, N);

    // ---- layer 2 (bf16 message table, alphas exact from out1) ----
    va_kernel<96, 6, 24><<<1, 768, 0, stream>>>(W2, a2s, a2d, va2s, va2d, 96);
    alphap_kernel<96><<<grid((long)N * 8, B), B, 0, stream>>>(out1, va2s, va2d, asp2, adp2, N);
    gemm_bf16_kernel<96, 144, 2><<<grid((long)(N / 2) * 36, B), B, 0, stream>>>(out1, W2, h2t, N);
    hipMemsetAsync(pooled, 0, 144 * sizeof(float), stream);
    gather2_kernel<<<grid(N, 16), 576, 0, stream>>>(off, esrc, asp2, adp2, h2t, pooled, N);

    // ---- normalize + linear ----
    final_kernel<<<1, 64, 0, stream>>>(pooled, Wd, bd, (float*)d_out);
}

// Round 6
// 569.989 us; speedup vs baseline: 1.4104x; 1.1070x over previous
//
#include <hip/hip_runtime.h>
#include <math.h>

#define NNODES 50000
#define NEDGES 1600000

__device__ __forceinline__ float lrelu(float v) { return v > 0.f ? v : 0.2f * v; }

__device__ __forceinline__ unsigned short f2bf(float f) {  // RNE f32->bf16
    unsigned u = __float_as_uint(f);
    u += 0x7FFFu + ((u >> 16) & 1u);
    return (unsigned short)(u >> 16);
}

// ---- pad x (N x 11) -> xp (N x 12, last col 0) ----
__global__ void padx_kernel(const float* __restrict__ x, float* __restrict__ xp, int N) {
    int t = blockIdx.x * blockDim.x + threadIdx.x;
    if (t >= N * 12) return;
    int n = t / 12, k = t - n * 12;
    xp[t] = (k < 11) ? x[n * 11 + k] : 0.f;
}

// ---- va[k][h] = sum_f W[k][h*F+f] * a[h][f], padded to 8 heads (0 beyond H) ----
template<int DIN, int H, int F>
__global__ void va_kernel(const float* __restrict__ W, const float* __restrict__ a_s,
                          const float* __restrict__ a_d, float* __restrict__ va_s,
                          float* __restrict__ va_d, int DINEFF) {
    int t = threadIdx.x;  // DIN*8 threads, 1 block
    if (t >= DIN * 8) return;
    int k = t / 8, h = t - k * 8;
    float s = 0.f, d = 0.f;
    if (h < H && k < DINEFF) {
        for (int f = 0; f < F; ++f) {
            float w = W[k * (H * F) + h * F + f];
            s = fmaf(w, a_s[h * F + f], s);
            d = fmaf(w, a_d[h * F + f], d);
        }
    }
    va_s[t] = s;
    va_d[t] = d;
}

// ---- asp[n*8+h] = sum_k X[n][k]*va_s[k][h]; adp likewise ----
template<int DIN>
__global__ void alphap_kernel(const float* __restrict__ X, const float* __restrict__ va_s,
                              const float* __restrict__ va_d, float* __restrict__ asp,
                              float* __restrict__ adp, int N) {
    __shared__ float vs[DIN * 8], vd[DIN * 8];
    for (int i = threadIdx.x; i < DIN * 8; i += blockDim.x) { vs[i] = va_s[i]; vd[i] = va_d[i]; }
    __syncthreads();
    int t = blockIdx.x * blockDim.x + threadIdx.x;
    if (t >= N * 8) return;
    int n = t / 8, h = t - n * 8;
    const float* xr = X + (size_t)n * DIN;
    float s = 0.f, d = 0.f;
    for (int k = 0; k < DIN; ++k) {
        float xv = xr[k];
        s = fmaf(xv, vs[k * 8 + h], s);
        d = fmaf(xv, vd[k * 8 + h], d);
    }
    asp[t] = s;
    adp[t] = d;
}

// ---- CSR build ----
__global__ void hist_kernel(const int* __restrict__ dst, int* __restrict__ cnt, int E) {
    int t = blockIdx.x * blockDim.x + threadIdx.x;
    if (t < E) atomicAdd(&cnt[dst[t]], 1);
}

__global__ void scan_kernel(int* __restrict__ cnt, int* __restrict__ off, int N) {
    __shared__ int ls[1024];
    int t = threadIdx.x;
    const int CH = (N + 1023) / 1024;
    int base = t * CH, lim = min(base + CH, N);
    int s = 0;
    for (int i = base; i < lim; ++i) s += cnt[i];
    ls[t] = s;
    __syncthreads();
    for (int o = 1; o < 1024; o <<= 1) {
        int u = (t >= o) ? ls[t - o] : 0;
        __syncthreads();
        ls[t] += u;
        __syncthreads();
    }
    int run = ls[t] - s;
    for (int i = base; i < lim; ++i) { int c = cnt[i]; off[i] = run; run += c; }
    if (t == 1023) off[N] = ls[1023];
    __syncthreads();
    for (int i = base; i < lim; ++i) cnt[i] = off[i];
}

__global__ void scatter_kernel(const int* __restrict__ src, const int* __restrict__ dst,
                               int* __restrict__ cur, int* __restrict__ esrc, int E) {
    int t = blockIdx.x * blockDim.x + threadIdx.x;
    if (t >= E) return;
    int pos = atomicAdd(&cur[dst[t]], 1);
    esrc[pos] = src[t];
}

// ---- layer-1 gather on raw x rows: aggX[n][h][12] = (sum_e att_h * xp[s]) / den_h ----
__global__ void gather1_kernel(const int* __restrict__ off, const int* __restrict__ esrc,
                               const float* __restrict__ asp, const float* __restrict__ adp,
                               const float* __restrict__ xp, float* __restrict__ aggX, int N) {
    int t = blockIdx.x * blockDim.x + threadIdx.x;
    if (t >= N * 3) return;
    int n = t / 3, j = t - n * 3;
    const float4 advA = *(const float4*)(adp + (size_t)n * 8);
    const float4 advB = *(const float4*)(adp + (size_t)n * 8 + 4);
    const float4* xp4 = (const float4*)xp;
    int p0 = off[n], p1 = off[n + 1];
    float4 ac0 = {0,0,0,0}, ac1 = {0,0,0,0}, ac2 = {0,0,0,0}, ac3 = {0,0,0,0}, ac4 = {0,0,0,0}, ac5 = {0,0,0,0};
    float d0 = 0, d1 = 0, d2 = 0, d3 = 0, d4 = 0, d5 = 0;
    for (int p = p0; p < p1; ++p) {
        int s = esrc[p];
        const float4 asA = *(const float4*)(asp + (size_t)s * 8);
        const float4 asB = *(const float4*)(asp + (size_t)s * 8 + 4);
        float4 xv = xp4[(size_t)s * 3 + j];
        float a0 = __expf(lrelu(asA.x + advA.x));
        float a1 = __expf(lrelu(asA.y + advA.y));
        float a2 = __expf(lrelu(asA.z + advA.z));
        float a3 = __expf(lrelu(asA.w + advA.w));
        float a4 = __expf(lrelu(asB.x + advB.x));
        float a5 = __expf(lrelu(asB.y + advB.y));
        d0 += a0; d1 += a1; d2 += a2; d3 += a3; d4 += a4; d5 += a5;
        ac0.x = fmaf(a0, xv.x, ac0.x); ac0.y = fmaf(a0, xv.y, ac0.y); ac0.z = fmaf(a0, xv.z, ac0.z); ac0.w = fmaf(a0, xv.w, ac0.w);
        ac1.x = fmaf(a1, xv.x, ac1.x); ac1.y = fmaf(a1, xv.y, ac1.y); ac1.z = fmaf(a1, xv.z, ac1.z); ac1.w = fmaf(a1, xv.w, ac1.w);
        ac2.x = fmaf(a2, xv.x, ac2.x); ac2.y = fmaf(a2, xv.y, ac2.y); ac2.z = fmaf(a2, xv.z, ac2.z); ac2.w = fmaf(a2, xv.w, ac2.w);
        ac3.x = fmaf(a3, xv.x, ac3.x); ac3.y = fmaf(a3, xv.y, ac3.y); ac3.z = fmaf(a3, xv.z, ac3.z); ac3.w = fmaf(a3, xv.w, ac3.w);
        ac4.x = fmaf(a4, xv.x, ac4.x); ac4.y = fmaf(a4, xv.y, ac4.y); ac4.z = fmaf(a4, xv.z, ac4.z); ac4.w = fmaf(a4, xv.w, ac4.w);
        ac5.x = fmaf(a5, xv.x, ac5.x); ac5.y = fmaf(a5, xv.y, ac5.y); ac5.z = fmaf(a5, xv.z, ac5.z); ac5.w = fmaf(a5, xv.w, ac5.w);
    }
    float4* o4 = (float4*)aggX;
    float r;
    r = 1.f / (d0 + 1e-12f); ac0.x *= r; ac0.y *= r; ac0.z *= r; ac0.w *= r; o4[((size_t)n * 6 + 0) * 3 + j] = ac0;
    r = 1.f / (d1 + 1e-12f); ac1.x *= r; ac1.y *= r; ac1.z *= r; ac1.w *= r; o4[((size_t)n * 6 + 1) * 3 + j] = ac1;
    r = 1.f / (d2 + 1e-12f); ac2.x *= r; ac2.y *= r; ac2.z *= r; ac2.w *= r; o4[((size_t)n * 6 + 2) * 3 + j] = ac2;
    r = 1.f / (d3 + 1e-12f); ac3.x *= r; ac3.y *= r; ac3.z *= r; ac3.w *= r; o4[((size_t)n * 6 + 3) * 3 + j] = ac3;
    r = 1.f / (d4 + 1e-12f); ac4.x *= r; ac4.y *= r; ac4.z *= r; ac4.w *= r; o4[((size_t)n * 6 + 4) * 3 + j] = ac4;
    r = 1.f / (d5 + 1e-12f); ac5.x *= r; ac5.y *= r; ac5.z *= r; ac5.w *= r; o4[((size_t)n * 6 + 5) * 3 + j] = ac5;
}

// ---- out1[n][96] = elu( aggX[n][h] @ W1[:, head block] ) ----
__global__ void gemmL1_kernel(const float* __restrict__ aggX, const float* __restrict__ W1,
                              float* __restrict__ out1, int N) {
    __shared__ float Wl[12 * 96];
    for (int i = threadIdx.x; i < 12 * 96; i += blockDim.x) Wl[i] = (i < 11 * 96) ? W1[i] : 0.f;
    __syncthreads();
    int t = blockIdx.x * blockDim.x + threadIdx.x;
    if (t >= N * 24) return;
    int n = t / 24, q = t - n * 24;
    int h = q / 4, c = q * 4;
    const float* ag = aggX + ((size_t)n * 6 + h) * 12;
    float4 acc = {0, 0, 0, 0};
#pragma unroll
    for (int k = 0; k < 12; ++k) {
        float xv = ag[k];
        acc.x = fmaf(xv, Wl[k * 96 + c + 0], acc.x);
        acc.y = fmaf(xv, Wl[k * 96 + c + 1], acc.y);
        acc.z = fmaf(xv, Wl[k * 96 + c + 2], acc.z);
        acc.w = fmaf(xv, Wl[k * 96 + c + 3], acc.w);
    }
    acc.x = acc.x > 0.f ? acc.x : expm1f(acc.x);
    acc.y = acc.y > 0.f ? acc.y : expm1f(acc.y);
    acc.z = acc.z > 0.f ? acc.z : expm1f(acc.z);
    acc.w = acc.w > 0.f ? acc.w : expm1f(acc.w);
    ((float4*)out1)[(size_t)n * 24 + q] = acc;
}

// ---- h2 = out1 @ W2, stored bf16 (RNE), thread = (node pair, quad) ----
// Launch with 1024-thread blocks: 55KB LDS x 2 blocks/CU = 32 waves/CU (100% occ).
template<int DIN, int C, int NPT>
__global__ void gemm_bf16_kernel(const float* __restrict__ X, const float* __restrict__ W,
                                 uint2* __restrict__ Out, int N) {
    constexpr int Q = C / 4;
    __shared__ float4 Wl[DIN * Q];
    for (int i = threadIdx.x; i < DIN * Q; i += blockDim.x) Wl[i] = ((const float4*)W)[i];
    __syncthreads();
    int t = blockIdx.x * blockDim.x + threadIdx.x;
    int g = t / Q, q = t - g * Q;
    int n0 = g * NPT;
    if (n0 >= N) return;
    const float* xr = X + (size_t)n0 * DIN;
    float4 acc[NPT];
#pragma unroll
    for (int u = 0; u < NPT; ++u) acc[u] = make_float4(0.f, 0.f, 0.f, 0.f);
#pragma unroll 4
    for (int k = 0; k < DIN; ++k) {
        float4 w = Wl[k * Q + q];
#pragma unroll
        for (int u = 0; u < NPT; ++u) {
            float xv = xr[(size_t)u * DIN + k];
            acc[u].x = fmaf(xv, w.x, acc[u].x);
            acc[u].y = fmaf(xv, w.y, acc[u].y);
            acc[u].z = fmaf(xv, w.z, acc[u].z);
            acc[u].w = fmaf(xv, w.w, acc[u].w);
        }
    }
#pragma unroll
    for (int u = 0; u < NPT; ++u) {
        uint2 pk;
        pk.x = (unsigned)f2bf(acc[u].x) | ((unsigned)f2bf(acc[u].y) << 16);
        pk.y = (unsigned)f2bf(acc[u].z) | ((unsigned)f2bf(acc[u].w) << 16);
        Out[(size_t)(n0 + u) * Q + q] = pk;
    }
}

// ---- layer-2 gather: 12 threads/node, 12 bf16 channels each (3 x uint2), fused elu+pool ----
// block = 384 threads = 32 nodes x 12 threads (6 waves)
__global__ void gather2_kernel(const int* __restrict__ off, const int* __restrict__ esrc,
                               const float* __restrict__ asp, const float* __restrict__ adp,
                               const uint2* __restrict__ h2t, float* __restrict__ pooled, int N) {
    __shared__ float sp[144];
    if (threadIdx.x < 144) sp[threadIdx.x] = 0.f;
    __syncthreads();
    int li = threadIdx.x;
    int node = blockIdx.x * 32 + li / 12;
    int j = li % 12;            // channels [12j, 12j+12)
    if (node < N) {
        int h = j >> 1;         // 24 channels per head, 2 threads per head
        float adv = adp[(size_t)node * 8 + h];
        int p0 = off[node], p1 = off[node + 1];
        float a0=0,a1=0,a2=0,a3=0,a4=0,a5=0,a6=0,a7=0,a8=0,a9=0,a10=0,a11=0;
        float den = 0.f;
        for (int p = p0; p < p1; ++p) {
            int s = esrc[p];
            float att = __expf(lrelu(asp[(size_t)s * 8 + h] + adv));
            den += att;
            const uint2* r = h2t + (size_t)s * 36 + 3 * j;
            uint2 v0 = r[0];
            uint2 v1 = r[1];
            uint2 v2 = r[2];
            a0  = fmaf(att, __uint_as_float(v0.x << 16),          a0);
            a1  = fmaf(att, __uint_as_float(v0.x & 0xFFFF0000u),  a1);
            a2  = fmaf(att, __uint_as_float(v0.y << 16),          a2);
            a3  = fmaf(att, __uint_as_float(v0.y & 0xFFFF0000u),  a3);
            a4  = fmaf(att, __uint_as_float(v1.x << 16),          a4);
            a5  = fmaf(att, __uint_as_float(v1.x & 0xFFFF0000u),  a5);
            a6  = fmaf(att, __uint_as_float(v1.y << 16),          a6);
            a7  = fmaf(att, __uint_as_float(v1.y & 0xFFFF0000u),  a7);
            a8  = fmaf(att, __uint_as_float(v2.x << 16),          a8);
            a9  = fmaf(att, __uint_as_float(v2.x & 0xFFFF0000u),  a9);
            a10 = fmaf(att, __uint_as_float(v2.y << 16),          a10);
            a11 = fmaf(att, __uint_as_float(v2.y & 0xFFFF0000u),  a11);
        }
        float rd = 1.f / (den + 1e-12f);
        float v;
        int cb = 12 * j;
        v = a0  * rd; v = v > 0.f ? v : expm1f(v); atomicAdd(&sp[cb + 0],  v);
        v = a1  * rd; v = v > 0.f ? v : expm1f(v); atomicAdd(&sp[cb + 1],  v);
        v = a2  * rd; v = v > 0.f ? v : expm1f(v); atomicAdd(&sp[cb + 2],  v);
        v = a3  * rd; v = v > 0.f ? v : expm1f(v); atomicAdd(&sp[cb + 3],  v);
        v = a4  * rd; v = v > 0.f ? v : expm1f(v); atomicAdd(&sp[cb + 4],  v);
        v = a5  * rd; v = v > 0.f ? v : expm1f(v); atomicAdd(&sp[cb + 5],  v);
        v = a6  * rd; v = v > 0.f ? v : expm1f(v); atomicAdd(&sp[cb + 6],  v);
        v = a7  * rd; v = v > 0.f ? v : expm1f(v); atomicAdd(&sp[cb + 7],  v);
        v = a8  * rd; v = v > 0.f ? v : expm1f(v); atomicAdd(&sp[cb + 8],  v);
        v = a9  * rd; v = v > 0.f ? v : expm1f(v); atomicAdd(&sp[cb + 9],  v);
        v = a10 * rd; v = v > 0.f ? v : expm1f(v); atomicAdd(&sp[cb + 10], v);
        v = a11 * rd; v = v > 0.f ? v : expm1f(v); atomicAdd(&sp[cb + 11], v);
    }
    __syncthreads();
    if (threadIdx.x < 144) atomicAdd(&pooled[threadIdx.x], sp[threadIdx.x]);
}

// ---- out = dot(pooled, Wd) / max(||pooled||, 1e-12) + bd ----
__global__ void final_kernel(const float* __restrict__ pooled, const float* __restrict__ Wd,
                             const float* __restrict__ bd, float* __restrict__ out) {
    int l = threadIdx.x;
    float ss = 0.f, dot = 0.f;
    for (int c = l; c < 144; c += 64) {
        float p = pooled[c];
        ss = fmaf(p, p, ss);
        dot = fmaf(p, Wd[c], dot);
    }
#pragma unroll
    for (int o = 32; o > 0; o >>= 1) {
        ss += __shfl_down(ss, o);
        dot += __shfl_down(dot, o);
    }
    if (l == 0) out[0] = dot / fmaxf(sqrtf(ss), 1e-12f) + bd[0];
}

extern "C" void kernel_launch(void* const* d_in, const int* in_sizes, int n_in,
                              void* d_out, int out_size, void* d_ws, size_t ws_size,
                              hipStream_t stream) {
    const float* x   = (const float*)d_in[0];
    const int*   src = (const int*)  d_in[1];
    const int*   dst = (const int*)  d_in[2];
    const float* W1  = (const float*)d_in[3];
    const float* a1s = (const float*)d_in[4];
    const float* a1d = (const float*)d_in[5];
    const float* W2  = (const float*)d_in[6];
    const float* a2s = (const float*)d_in[7];
    const float* a2d = (const float*)d_in[8];
    const float* Wd  = (const float*)d_in[9];
    const float* bd  = (const float*)d_in[10];

    const int N = NNODES, E = NEDGES;
    float* ws = (float*)d_ws;
    float* xp    = ws;                         // N*12
    float* asp1  = xp + (size_t)N * 12;        // N*8
    float* adp1  = asp1 + (size_t)N * 8;       // N*8
    float* aggX  = adp1 + (size_t)N * 8;       // N*72
    float* out1  = aggX + (size_t)N * 72;      // N*96
    uint2* h2t   = (uint2*)(out1 + (size_t)N * 96);   // N*36 uint2 (= N*144 bf16)
    float* asp2  = out1 + (size_t)N * 96 + (size_t)N * 72;  // N*8
    float* adp2  = asp2 + (size_t)N * 8;       // N*8
    float* va1s  = adp2 + (size_t)N * 8;       // 96
    float* va1d  = va1s + 96;                  // 96
    float* va2s  = va1d + 96;                  // 768
    float* va2d  = va2s + 768;                 // 768
    float* pooled = va2d + 768;                // 144
    int*   off   = (int*)(pooled + 144);       // N+1
    int*   cur   = off + (N + 1);              // N
    int*   esrc  = cur + N;                    // E

    const int B = 256;
    auto grid = [](long total, int b) { return (int)((total + b - 1) / b); };

    // ---- CSR build ----
    hipMemsetAsync(cur, 0, (size_t)N * sizeof(int), stream);
    hist_kernel<<<grid(E, B), B, 0, stream>>>(dst, cur, E);
    scan_kernel<<<1, 1024, 0, stream>>>(cur, off, N);
    scatter_kernel<<<grid(E, B), B, 0, stream>>>(src, dst, cur, esrc, E);

    // ---- layer 1 (gather raw x, GEMM after) ----
    padx_kernel<<<grid((long)N * 12, B), B, 0, stream>>>(x, xp, N);
    va_kernel<12, 6, 16><<<1, 96, 0, stream>>>(W1, a1s, a1d, va1s, va1d, 11);
    alphap_kernel<12><<<grid((long)N * 8, B), B, 0, stream>>>(xp, va1s, va1d, asp1, adp1, N);
    gather1_kernel<<<grid((long)N * 3, B), B, 0, stream>>>(off, esrc, asp1, adp1, xp, aggX, N);
    gemmL1_kernel<<<grid((long)N * 24, B), B, 0, stream>>>(aggX, W1, out1, N);

    // ---- layer 2 (bf16 message table, alphas exact from out1) ----
    va_kernel<96, 6, 24><<<1, 768, 0, stream>>>(W2, a2s, a2d, va2s, va2d, 96);
    alphap_kernel<96><<<grid((long)N * 8, B), B, 0, stream>>>(out1, va2s, va2d, asp2, adp2, N);
    gemm_bf16_kernel<96, 144, 2><<<grid((long)(N / 2) * 36, 1024), 1024, 0, stream>>>(out1, W2, h2t, N);
    hipMemsetAsync(pooled, 0, 144 * sizeof(float), stream);
    gather2_kernel<<<grid(N, 32), 384, 0, stream>>>(off, esrc, asp2, adp2, h2t, pooled, N);

    // ---- normalize + linear ----
    final_kernel<<<1, 64, 0, stream>>>(pooled, Wd, bd, (float*)d_out);
}